// Round 1
// 295.651 us; speedup vs baseline: 1.1192x; 1.1192x over previous
//
#include <hip/hip_runtime.h>
#include <hip/hip_bf16.h>

// Problem: B=4, S=4096, H=16, D=64. Per (b,s): 16x16 attention over HEADS.
//   scores = (Q @ K^T)/8 ; attn = softmax(scores, g) ; out = (attn @ V) * mask
// Inputs: qkv fp32 [npos][3][16][64]; key_padding_mask (format auto-detected:
// bool bytes / int32 / int64). Output: fp32 [npos][16][64].
// One wave per position. QK^T and PV use bf16 hi/lo split MFMA (fp32-accurate).

typedef __attribute__((ext_vector_type(8))) short short8;
typedef __attribute__((ext_vector_type(4))) float floatx4;

static __device__ __forceinline__ short f2bf(float x) {
    union { __hip_bfloat16 b; short s; } u; u.b = __float2bfloat16(x);  // RNE
    return u.s;
}
static __device__ __forceinline__ float bf2f(short s) {
    union { float f; unsigned int u; } u;
    u.u = ((unsigned int)(unsigned short)s) << 16;
    return u.f;
}
// split 8 consecutive floats into bf16 hi + bf16 residual fragments
static __device__ __forceinline__ void split8(floatx4 a, floatx4 b,
                                              short8& hi, short8& lo) {
    float v[8] = {a[0], a[1], a[2], a[3], b[0], b[1], b[2], b[3]};
    #pragma unroll
    for (int j = 0; j < 8; ++j) {
        short h = f2bf(v[j]);
        hi[j] = h;
        lo[j] = f2bf(v[j] - bf2f(h));
    }
}

// ---- mask storage-format detector: 0 = 1-byte bool, 1 = int32, 2 = int64 ---
// Rewritten: 1024 threads, phase-1 vectorized as uint4 (16B/lane). For
// npos=16384 phase-1 is ONE iteration per thread instead of 64 scalar
// latency-serialized loads on a single CU. Phase-2 stays conditional on
// found1==0 to preserve the original's OOB-safety semantics (it only reads
// past npos bytes when the data already proved the buffer is int32/int64).
__global__ __launch_bounds__(1024) void detect_mask_fmt(
    const unsigned char* __restrict__ mb, int npos, int* __restrict__ flag)
{
    __shared__ int found1, found2;
    if (threadIdx.x == 0) { found1 = 0; found2 = 0; }
    __syncthreads();

    int l1 = 0;
    const int nvec = npos >> 4;                 // full 16B chunks
    const uint4* v = (const uint4*)mb;
    for (int i = threadIdx.x; i < nvec; i += blockDim.x) {
        uint4 w = v[i];
        // bytes at index %4 != 0 are bits [8:32) of each little-endian dword
        if ((w.x | w.y | w.z | w.w) & 0xFFFFFF00u) l1 = 1;
    }
    for (int i = (nvec << 4) + threadIdx.x; i < npos; i += blockDim.x)
        if ((i & 3) != 0 && mb[i] != 0) l1 = 1;
    if (l1) atomicOr(&found1, 1);
    __syncthreads();

    if (found1 == 0) {                          // block-uniform branch
        int l2 = 0;
        for (int i = threadIdx.x; i < npos / 2; i += blockDim.x)
            if (mb[8 * i + 4] != 0) l2 = 1;
        if (l2) atomicOr(&found2, 1);
    }
    __syncthreads();
    if (threadIdx.x == 0) *flag = found1 ? 0 : (found2 ? 1 : 2);
}

__global__ __launch_bounds__(256) void fa_heads_kernel(
    const float* __restrict__ qkv,              // [npos][3][16][64] fp32
    const unsigned char* __restrict__ maskraw,  // [npos] bool/int32/int64
    const int* __restrict__ fmt,                // from detector
    float* __restrict__ out,                    // [npos][16][64] fp32
    int npos)
{
    const int wid = (blockIdx.x << 2) + (threadIdx.x >> 6);  // wave = position
    if (wid >= npos) return;
    const int lane = threadIdx.x & 63;
    const int t  = lane & 15;
    const int qa = lane >> 4;

    const float* base = qkv + (size_t)wid * 3072;
    const float* Qp = base;
    const float* Kp = base + 1024;
    const float* Vp = base + 2048;

    // ---- mask (format-dispatched) — hoisted so its latency is hidden -------
    const int f = *fmt;   // wave-uniform
    int mi;
    if (f == 0)       mi = (int)maskraw[wid];
    else if (f == 1)  mi = ((const int*)maskraw)[wid];
    else              mi = (int)(((const long long*)maskraw)[wid] != 0);
    const float mv = (mi != 0) ? 1.0f : 0.0f;

    // ---- fragment loads (fp32, 16B-aligned float4 pairs) -------------------
    // A[m=lane&15][k=8*qa+j] ; first MFMA contracts d=0..31, second d=32..63
    const int fo = t * 64 + qa * 8;
    short8 khi0, klo0, khi1, klo1, qhi0, qlo0, qhi1, qlo1;
    split8(*(const floatx4*)(Kp + fo),      *(const floatx4*)(Kp + fo + 4),  khi0, klo0);
    split8(*(const floatx4*)(Kp + fo + 32), *(const floatx4*)(Kp + fo + 36), khi1, klo1);
    split8(*(const floatx4*)(Qp + fo),      *(const floatx4*)(Qp + fo + 4),  qhi0, qlo0);
    split8(*(const floatx4*)(Qp + fo + 32), *(const floatx4*)(Qp + fo + 36), qhi1, qlo1);

    // ---- V loads + bf16 split, hoisted BEFORE QK^T so the 32 scalar global
    // loads overlap with the MFMA/softmax compute tail instead of following it
    short8 bvh[4], bvl[4];
    #pragma unroll
    for (int c = 0; c < 4; ++c) {
        #pragma unroll
        for (int j = 0; j < 8; ++j) {
            int g = (8 * qa + j) & 15;           // A is zero where g wraps
            float vv = Vp[g * 64 + c * 16 + t];
            short h = f2bf(vv);
            bvh[c][j] = h;
            bvl[c][j] = f2bf(vv - bf2f(h));
        }
    }

    // ---- S^T = K * Q^T, 3-term split precision -----------------------------
    // two independent accumulator chains (d=0..31 and d=32..63) + final add:
    // halves the serial MFMA dependence depth vs one 6-deep chain.
    floatx4 sa = {0.f, 0.f, 0.f, 0.f};
    floatx4 sb = {0.f, 0.f, 0.f, 0.f};
    sa = __builtin_amdgcn_mfma_f32_16x16x32_bf16(khi0, qhi0, sa, 0, 0, 0);
    sb = __builtin_amdgcn_mfma_f32_16x16x32_bf16(khi1, qhi1, sb, 0, 0, 0);
    sa = __builtin_amdgcn_mfma_f32_16x16x32_bf16(khi0, qlo0, sa, 0, 0, 0);
    sb = __builtin_amdgcn_mfma_f32_16x16x32_bf16(khi1, qlo1, sb, 0, 0, 0);
    sa = __builtin_amdgcn_mfma_f32_16x16x32_bf16(klo0, qhi0, sa, 0, 0, 0);
    sb = __builtin_amdgcn_mfma_f32_16x16x32_bf16(klo1, qhi1, sb, 0, 0, 0);
    floatx4 sc;
    sc[0] = sa[0] + sb[0]; sc[1] = sa[1] + sb[1];
    sc[2] = sa[2] + sb[2]; sc[3] = sa[3] + sb[3];
    // D layout: row = 4*qa + r = g, col = t = h  => sc[r] = raw_scores[h=t][g=4qa+r]

    // ---- softmax over g ----------------------------------------------------
    float s0 = sc[0] * 0.125f, s1 = sc[1] * 0.125f;
    float s2 = sc[2] * 0.125f, s3 = sc[3] * 0.125f;
    float m = fmaxf(fmaxf(s0, s1), fmaxf(s2, s3));
    m = fmaxf(m, __shfl_xor(m, 16));
    m = fmaxf(m, __shfl_xor(m, 32));
    float e0 = __expf(s0 - m), e1 = __expf(s1 - m);
    float e2 = __expf(s2 - m), e3 = __expf(s3 - m);
    float l = e0 + e1 + e2 + e3;
    l += __shfl_xor(l, 16);
    l += __shfl_xor(l, 32);
    float rl = 1.0f / l;
    float p0 = e0 * rl, p1 = e1 * rl, p2 = e2 * rl, p3 = e3 * rl;
    // lane holds attn[h=t][g=4*qa+r]

    // ---- redistribute attn into PV A-operand layout ------------------------
    // A[m=t][k=8qa+j] = attn[h=t][g=8qa+j]; quads 2,3 zero-padded (K=16<32)
    int slo = (t + 32 * qa) & 63;
    int shi = (slo + 16) & 63;
    float av[8];
    av[0] = __shfl(p0, slo); av[1] = __shfl(p1, slo);
    av[2] = __shfl(p2, slo); av[3] = __shfl(p3, slo);
    av[4] = __shfl(p0, shi); av[5] = __shfl(p1, shi);
    av[6] = __shfl(p2, shi); av[7] = __shfl(p3, shi);
    const bool live = (qa < 2);
    short8 aph, apl;
    #pragma unroll
    for (int j = 0; j < 8; ++j) {
        short h = live ? f2bf(av[j]) : (short)0;
        aph[j] = h;
        apl[j] = live ? f2bf(av[j] - bf2f(h)) : (short)0;
    }

    // ---- PV: out[:, 16c:16c+16] = attn @ V[:, 16c:16c+16], split precision -
    // hi*hi runs as its own chain; (hi*lo + lo*hi) as a second chain; add.
    floatx4 o[4];
    #pragma unroll
    for (int c = 0; c < 4; ++c) {
        floatx4 z = {0.f, 0.f, 0.f, 0.f};
        floatx4 w = {0.f, 0.f, 0.f, 0.f};
        z = __builtin_amdgcn_mfma_f32_16x16x32_bf16(aph, bvh[c], z, 0, 0, 0);
        w = __builtin_amdgcn_mfma_f32_16x16x32_bf16(aph, bvl[c], w, 0, 0, 0);
        w = __builtin_amdgcn_mfma_f32_16x16x32_bf16(apl, bvh[c], w, 0, 0, 0);
        o[c][0] = z[0] + w[0]; o[c][1] = z[1] + w[1];
        o[c][2] = z[2] + w[2]; o[c][3] = z[3] + w[3];
    }
    // D layout: row = 4qa + r = h, col = t = d%16

    // ---- fp32 store --------------------------------------------------------
    float* op = out + (size_t)wid * 1024;
    #pragma unroll
    for (int c = 0; c < 4; ++c) {
        #pragma unroll
        for (int r = 0; r < 4; ++r) {
            op[(4 * qa + r) * 64 + c * 16 + t] = o[c][r] * mv;
        }
    }
}

extern "C" void kernel_launch(void* const* d_in, const int* in_sizes, int n_in,
                              void* d_out, int out_size, void* d_ws, size_t ws_size,
                              hipStream_t stream) {
    const float* qkv = (const float*)d_in[0];
    const unsigned char* maskraw = (const unsigned char*)d_in[1];
    float* out = (float*)d_out;
    int* fmt = (int*)d_ws;
    const int npos = in_sizes[1];               // B*S = 16384 positions

    detect_mask_fmt<<<1, 1024, 0, stream>>>(maskraw, npos, fmt);

    const int blocks = (npos + 3) / 4;          // 4 waves (positions) per block
    fa_heads_kernel<<<blocks, 256, 0, stream>>>(qkv, maskraw, fmt, out, npos);
}